// Round 9
// baseline (306.372 us; speedup 1.0000x reference)
//
#include <hip/hip_runtime.h>
#include <hip/hip_bf16.h>

#define L_DIM 32
#define N_DIM 1024
#define D_DIM 768
#define K_DIM 16
#define I_DIM 64
#define O_DIM 64
#define EPSF 1e-8f
#define PX 72   // padded LDS row (bf16 elems): 144 B, 16B-aligned, 2-way banks only

typedef unsigned short u16;
typedef __attribute__((ext_vector_type(8))) short short8;   // 8 bf16 (4 VGPRs)
typedef __attribute__((ext_vector_type(4))) float f32x4;
#define MFMA __builtin_amdgcn_mfma_f32_16x16x32_bf16

__device__ __forceinline__ float bf2f(u16 v) {
    union { unsigned int u; float f; } x; x.u = ((unsigned int)v) << 16; return x.f;
}
__device__ __forceinline__ u16 f2bf(float f) {
    union { float f; unsigned int u; } x; x.f = f;
    unsigned int u = x.u;
    u += 0x7FFFu + ((u >> 16) & 1u);   // RNE
    return (u16)(u >> 16);
}
__device__ __forceinline__ void split2(float v, u16& h, u16& l) {
    u16 hh = f2bf(v);
    h = hh;
    l = f2bf(v - bf2f(hh));
}

// ---------------------------------------------------------------------------
// Prep 1: Wcap [l][d][i] f32  ->  ws [l][i][d] bf16 hi/lo.  grid (12, 32).
// ---------------------------------------------------------------------------
__global__ __launch_bounds__(256) void prep_wcap(
    const float* __restrict__ W, u16* __restrict__ H, u16* __restrict__ Lo)
{
    const int l = blockIdx.y, d0 = blockIdx.x * 64, t = threadIdx.x;
    __shared__ float tile[64][65];
    #pragma unroll
    for (int p = 0; p < 4; p++) {
        int dd = p * 16 + (t >> 4), i4 = (t & 15) * 4;
        float4 v = *(const float4*)&W[((size_t)l * D_DIM + d0 + dd) * I_DIM + i4];
        tile[dd][i4] = v.x; tile[dd][i4+1] = v.y; tile[dd][i4+2] = v.z; tile[dd][i4+3] = v.w;
    }
    __syncthreads();
    #pragma unroll
    for (int p = 0; p < 4; p++) {
        int i = p * 16 + (t >> 4), dd0 = (t & 15) * 4;
        u16 h[4], lo[4];
        #pragma unroll
        for (int j = 0; j < 4; j++) split2(tile[dd0 + j][i], h[j], lo[j]);
        size_t base = ((size_t)l * I_DIM + i) * D_DIM + d0 + dd0;
        uint2 ph; ph.x = h[0] | ((unsigned)h[1] << 16); ph.y = h[2] | ((unsigned)h[3] << 16);
        uint2 pl; pl.x = lo[0] | ((unsigned)lo[1] << 16); pl.y = lo[2] | ((unsigned)lo[3] << 16);
        *(uint2*)&H[base] = ph;
        *(uint2*)&Lo[base] = pl;
    }
}

// ---------------------------------------------------------------------------
// Prep 2: Wvote [l][k][i][o] f32 -> ws [l][k][o][i] bf16 hi/lo. grid (16, 32).
// ---------------------------------------------------------------------------
__global__ __launch_bounds__(256) void prep_wvote(
    const float* __restrict__ W, u16* __restrict__ H, u16* __restrict__ Lo)
{
    const int l = blockIdx.y, k = blockIdx.x, t = threadIdx.x;
    __shared__ float tile[64][65];
    #pragma unroll
    for (int p = 0; p < 4; p++) {
        int i = p * 16 + (t >> 4), o4 = (t & 15) * 4;
        float4 v = *(const float4*)&W[(((size_t)l * K_DIM + k) * I_DIM + i) * O_DIM + o4];
        tile[i][o4] = v.x; tile[i][o4+1] = v.y; tile[i][o4+2] = v.z; tile[i][o4+3] = v.w;
    }
    __syncthreads();
    #pragma unroll
    for (int p = 0; p < 4; p++) {
        int o = p * 16 + (t >> 4), i0 = (t & 15) * 4;
        u16 h[4], lo[4];
        #pragma unroll
        for (int j = 0; j < 4; j++) split2(tile[i0 + j][o], h[j], lo[j]);
        size_t base = (((size_t)l * K_DIM + k) * O_DIM + o) * I_DIM + i0;
        uint2 ph; ph.x = h[0] | ((unsigned)h[1] << 16); ph.y = h[2] | ((unsigned)h[3] << 16);
        uint2 pl; pl.x = lo[0] | ((unsigned)lo[1] << 16); pl.y = lo[2] | ((unsigned)lo[3] << 16);
        *(uint2*)&H[base] = ph;
        *(uint2*)&Lo[base] = pl;
    }
}

// ---------------------------------------------------------------------------
// Kernel A (MFMA, 64-n tile, double-buffered staging):
//   mu[l,nl,i] = gelu(x·Wcap + Bcap); fa = sigmoid(x·Wscore+Bs)·mask
// grid (nchunk/64, 32), block 256. Wave w owns i-tile w; 4 n-tiles.
// One barrier per chunk; chunk ch+1 staged while MFMAs run on ch.
// ---------------------------------------------------------------------------
__global__ __launch_bounds__(256) void kernelA(
    const float* __restrict__ x, const float* __restrict__ mask,
    const float* __restrict__ Wscore, const float* __restrict__ Bscore,
    const u16* __restrict__ WcH, const u16* __restrict__ WcL,
    const float* __restrict__ Bcap,
    float* __restrict__ mu_out, float* __restrict__ fa_out,
    int nbase, int nchunk)
{
    const int l   = blockIdx.y;
    const int n0l = blockIdx.x * 64;
    const int t    = threadIdx.x;
    const int w    = t >> 6;
    const int lane = t & 63;
    const int quad = lane >> 4;
    const int ln16 = lane & 15;

    __shared__ u16 xh[2][64][PX], xl[2][64][PX];
    __shared__ float wsc_s[D_DIM];
    __shared__ float bcap_s[64];

    for (int i = t; i < D_DIM; i += 256) wsc_s[i] = Wscore[l * D_DIM + i];
    if (t < 64) bcap_s[t] = Bcap[l * I_DIM + t];

    const int sn = t >> 4;            // staging row within 16-row group
    const int sd = (t & 15) * 4;      // staging d-offset

    // stage chunk 0 into buffer 0
    #pragma unroll
    for (int p = 0; p < 4; p++) {
        int n = p * 16 + sn;
        float4 v = *(const float4*)&x[((size_t)(nbase + n0l + n) * L_DIM + l) * D_DIM + sd];
        u16 h[4], lo[4];
        split2(v.x, h[0], lo[0]); split2(v.y, h[1], lo[1]);
        split2(v.z, h[2], lo[2]); split2(v.w, h[3], lo[3]);
        uint2 ph; ph.x = h[0] | ((unsigned)h[1] << 16); ph.y = h[2] | ((unsigned)h[3] << 16);
        uint2 pl; pl.x = lo[0] | ((unsigned)lo[1] << 16); pl.y = lo[2] | ((unsigned)lo[3] << 16);
        *(uint2*)&xh[0][n][sd] = ph;
        *(uint2*)&xl[0][n][sd] = pl;
    }
    __syncthreads();

    f32x4 acc[4] = {{0.f,0.f,0.f,0.f},{0.f,0.f,0.f,0.f},{0.f,0.f,0.f,0.f},{0.f,0.f,0.f,0.f}};
    float apart = 0.f;

    for (int ch = 0; ch < 12; ch++) {
        const int buf = ch & 1;
        const int k0 = ch * 64;

        // prefetch chunk ch+1 into buf^1 (overlaps with MFMA below)
        if (ch + 1 < 12) {
            const int k1 = k0 + 64;
            #pragma unroll
            for (int p = 0; p < 4; p++) {
                int n = p * 16 + sn;
                float4 v = *(const float4*)&x[((size_t)(nbase + n0l + n) * L_DIM + l) * D_DIM + k1 + sd];
                u16 h[4], lo[4];
                split2(v.x, h[0], lo[0]); split2(v.y, h[1], lo[1]);
                split2(v.z, h[2], lo[2]); split2(v.w, h[3], lo[3]);
                uint2 ph; ph.x = h[0] | ((unsigned)h[1] << 16); ph.y = h[2] | ((unsigned)h[3] << 16);
                uint2 pl; pl.x = lo[0] | ((unsigned)lo[1] << 16); pl.y = lo[2] | ((unsigned)lo[3] << 16);
                *(uint2*)&xh[buf ^ 1][n][sd] = ph;
                *(uint2*)&xl[buf ^ 1][n][sd] = pl;
            }
        }

        {   // fa partial: 4 threads per row; row fn = t>>2, slice (t&3)*16
            const int fn = t >> 2, fs = (t & 3) * 16;
            float ss = 0.f;
            #pragma unroll
            for (int j = 0; j < 16; j++) {
                int dd = fs + j;
                ss += (bf2f(xh[buf][fn][dd]) + bf2f(xl[buf][fn][dd])) * wsc_s[k0 + dd];
            }
            apart += ss;
        }

        #pragma unroll
        for (int ks = 0; ks < 2; ks++) {
            const int kk = ks * 32;
            size_t wbase = ((size_t)l * I_DIM + (w * 16 + ln16)) * D_DIM + k0 + kk + quad * 8;
            short8 ah = *(const short8*)&WcH[wbase];
            short8 al = *(const short8*)&WcL[wbase];
            #pragma unroll
            for (int c = 0; c < 4; c++) {
                const int n = c * 16 + ln16;
                short8 bh = *(const short8*)&xh[buf][n][kk + quad * 8];
                short8 bl = *(const short8*)&xl[buf][n][kk + quad * 8];
                acc[c] = MFMA(ah, bh, acc[c], 0, 0, 0);
                acc[c] = MFMA(ah, bl, acc[c], 0, 0, 0);
                acc[c] = MFMA(al, bh, acc[c], 0, 0, 0);
            }
        }
        __syncthreads();
    }

    // fa reduce across the 4 threads sharing a row (lane bits 0,1)
    apart += __shfl_xor(apart, 1, 64);
    apart += __shfl_xor(apart, 2, 64);
    if ((t & 3) == 0) {
        int n = t >> 2;
        float a = apart + Bscore[l];
        float sig = 1.f / (1.f + expf(-a));
        float m = mask[(size_t)(nbase + n0l + n) * L_DIM + l];
        fa_out[(size_t)l * nchunk + n0l + n] = sig * m;
    }

    // mu epilogue: D row i = w*16 + quad*4 + r; col n = c*16 + ln16
    #pragma unroll
    for (int c = 0; c < 4; c++) {
        const int n = c * 16 + ln16;
        const int i0 = w * 16 + quad * 4;
        float4 o;
        float* op = (float*)&o;
        #pragma unroll
        for (int r = 0; r < 4; r++) {
            float v = acc[c][r] + bcap_s[i0 + r];
            op[r] = 0.5f * v * (1.f + erff(v * 0.70710678118f));
        }
        *(float4*)&mu_out[((size_t)l * nchunk + n0l + n) * I_DIM + i0] = o;
    }
}

// ---------------------------------------------------------------------------
// Kernel B (MFMA): V[l][k][nl][o] = mu·Wvote + Bvote (f32). grid (nchunk/64,16,32).
// ---------------------------------------------------------------------------
__global__ __launch_bounds__(256) void kernelB(
    const float* __restrict__ mu_in,
    const u16* __restrict__ WvH, const u16* __restrict__ WvL,
    const float* __restrict__ Bvote,
    float* __restrict__ V, int nchunk)
{
    const int l   = blockIdx.z;
    const int k   = blockIdx.y;
    const int n0l = blockIdx.x * 64;
    const int t    = threadIdx.x;
    const int w    = t >> 6;
    const int lane = t & 63;
    const int quad = lane >> 4;
    const int ln16 = lane & 15;

    __shared__ u16 mh[64][PX], ml[64][PX];
    __shared__ float bvote_s[64];

    if (t < 64) bvote_s[t] = Bvote[((size_t)l * K_DIM + k) * O_DIM + t];

    #pragma unroll
    for (int p = 0; p < 4; p++) {
        int n = p * 16 + (t >> 4), i0 = (t & 15) * 4;
        float4 v = *(const float4*)&mu_in[((size_t)l * nchunk + n0l + n) * I_DIM + i0];
        u16 h[4], lo[4];
        split2(v.x, h[0], lo[0]); split2(v.y, h[1], lo[1]);
        split2(v.z, h[2], lo[2]); split2(v.w, h[3], lo[3]);
        uint2 ph; ph.x = h[0] | ((unsigned)h[1] << 16); ph.y = h[2] | ((unsigned)h[3] << 16);
        uint2 pl; pl.x = lo[0] | ((unsigned)lo[1] << 16); pl.y = lo[2] | ((unsigned)lo[3] << 16);
        *(uint2*)&mh[n][i0] = ph;
        *(uint2*)&ml[n][i0] = pl;
    }
    __syncthreads();

    f32x4 acc[4] = {{0.f,0.f,0.f,0.f},{0.f,0.f,0.f,0.f},{0.f,0.f,0.f,0.f},{0.f,0.f,0.f,0.f}};

    #pragma unroll
    for (int ks = 0; ks < 2; ks++) {
        const int kk = ks * 32;
        size_t wbase = (((size_t)l * K_DIM + k) * O_DIM + (w * 16 + ln16)) * I_DIM + kk + quad * 8;
        short8 ah = *(const short8*)&WvH[wbase];
        short8 al = *(const short8*)&WvL[wbase];
        #pragma unroll
        for (int c = 0; c < 4; c++) {
            const int n = c * 16 + ln16;
            short8 bh = *(const short8*)&mh[n][kk + quad * 8];
            short8 bl = *(const short8*)&ml[n][kk + quad * 8];
            acc[c] = MFMA(ah, bh, acc[c], 0, 0, 0);
            acc[c] = MFMA(ah, bl, acc[c], 0, 0, 0);
            acc[c] = MFMA(al, bh, acc[c], 0, 0, 0);
        }
    }

    // D row = o = w*16 + quad*4 + r; col n = c*16 + ln16.  V[l][k][n][o].
    #pragma unroll
    for (int c = 0; c < 4; c++) {
        const int n = c * 16 + ln16;
        const int o0 = w * 16 + quad * 4;
        float4 o;
        o.x = acc[c][0] + bvote_s[o0];
        o.y = acc[c][1] + bvote_s[o0 + 1];
        o.z = acc[c][2] + bvote_s[o0 + 2];
        o.w = acc[c][3] + bvote_s[o0 + 3];
        *(float4*)&V[(((size_t)l * K_DIM + k) * nchunk + n0l + n) * O_DIM + o0] = o;
    }
}

// ---------------------------------------------------------------------------
// Kernel C: EM routing, one block per n. V[l][k][n][o] (round-7 layout).
// Thread t: k = t>>4, o in [og,og+4). Parallel softmax; single-pass moments.
// ---------------------------------------------------------------------------
__global__ __launch_bounds__(256) void kernelC(
    const float* __restrict__ V, const float* __restrict__ fa_in,
    const float* __restrict__ beta_use, const float* __restrict__ beta_ign,
    const int* __restrict__ iters_p,
    float* __restrict__ out, int nbase, int nchunk)
{
    const int nl = blockIdx.x;
    const int ng = nbase + nl;
    const int t  = threadIdx.x;
    const int k  = t >> 4;
    const int og = (t & 15) << 2;
    int iters = iters_p[0];
    if (iters < 0 || iters > 16) iters = 3;

    __shared__ float fa_s[32];
    __shared__ float bu_s[32];
    __shared__ float R_s[32][17];
    __shared__ float sc_s[32][17];

    if (t < 32) {
        fa_s[t] = fa_in[(size_t)t * nchunk + nl];
        bu_s[t] = beta_use[t];
    }
    for (int idx = t; idx < 512; idx += 256)
        R_s[idx >> 4][idx & 15] = 1.f / 16.f;
    const float bi_k = beta_ign[k];

    float Vr[32][4];
    #pragma unroll
    for (int l = 0; l < 32; l++) {
        float4 v = *(const float4*)&V[(((size_t)l * K_DIM + k) * nchunk + nl) * O_DIM + og];
        Vr[l][0] = v.x; Vr[l][1] = v.y; Vr[l][2] = v.z; Vr[l][3] = v.w;
    }
    __syncthreads();

    float mu_r[4] = {0.f, 0.f, 0.f, 0.f};
    float var_r[4] = {0.f, 0.f, 0.f, 0.f};
    float a_r = 0.f;

    for (int it = 0; it < iters; it++) {
        if (it > 0) {
            float inv2v[4], lvp = 0.f;
            #pragma unroll
            for (int j = 0; j < 4; j++) {
                inv2v[j] = 1.f / (2.f * var_r[j] + EPSF);
                lvp += logf(var_r[j] + EPSF);
            }
            lvp += __shfl_xor(lvp, 1, 64);
            lvp += __shfl_xor(lvp, 2, 64);
            lvp += __shfl_xor(lvp, 4, 64);
            lvp += __shfl_xor(lvp, 8, 64);
            float ls = fminf(a_r, 0.f) - log1pf(expf(-fabsf(a_r)));
            const float cst = ls - 1.f - 1.57079632679f - 0.5f * lvp;
            #pragma unroll
            for (int l = 0; l < 32; l++) {
                float s = 0.f;
                #pragma unroll
                for (int j = 0; j < 4; j++) {
                    float d = Vr[l][j] - mu_r[j];
                    s += d * d * inv2v[j];
                }
                s = -s;
                s += __shfl_xor(s, 1, 64);
                s += __shfl_xor(s, 2, 64);
                s += __shfl_xor(s, 4, 64);
                s += __shfl_xor(s, 8, 64);
                if ((t & 15) == 0) sc_s[l][k] = s + cst;
            }
            __syncthreads();
            {   // parallel softmax over k: row lr = t>>3, 8 threads/row, 2 k each
                const int lr = t >> 3;
                const int c2 = (t & 7) * 2;
                float s0 = sc_s[lr][c2], s1 = sc_s[lr][c2 + 1];
                float m = fmaxf(s0, s1);
                m = fmaxf(m, __shfl_xor(m, 1, 64));
                m = fmaxf(m, __shfl_xor(m, 2, 64));
                m = fmaxf(m, __shfl_xor(m, 4, 64));
                float e0 = expf(s0 - m), e1 = expf(s1 - m);
                float sum = e0 + e1;
                sum += __shfl_xor(sum, 1, 64);
                sum += __shfl_xor(sum, 2, 64);
                sum += __shfl_xor(sum, 4, 64);
                float inv = 1.f / sum;
                R_s[lr][c2]     = e0 * inv;
                R_s[lr][c2 + 1] = e1 * inv;
            }
            __syncthreads();
        }
        // single-pass moments: var = E[V^2] - mu^2
        float denom = EPSF, a_acc = 0.f;
        float mu_a[4] = {0.f, 0.f, 0.f, 0.f};
        float v2_a[4] = {0.f, 0.f, 0.f, 0.f};
        #pragma unroll
        for (int l = 0; l < 32; l++) {
            float Du = fa_s[l] * R_s[l][k];
            denom += Du;
            a_acc += bu_s[l] * Du - bi_k * (fa_s[l] - Du);
            #pragma unroll
            for (int j = 0; j < 4; j++) {
                float dv = Du * Vr[l][j];
                mu_a[j] += dv;
                v2_a[j] += dv * Vr[l][j];
            }
        }
        float invd = 1.f / denom;
        #pragma unroll
        for (int j = 0; j < 4; j++) {
            mu_r[j] = mu_a[j] * invd;
            var_r[j] = fmaxf(v2_a[j] * invd - mu_r[j] * mu_r[j], 0.f);
        }
        a_r = a_acc;
    }

    if ((t & 15) == 0) out[(size_t)ng * K_DIM + k] = a_r;
    float4 o4;
    o4.x = mu_r[0]; o4.y = mu_r[1]; o4.z = mu_r[2]; o4.w = mu_r[3];
    *(float4*)&out[(size_t)N_DIM * K_DIM + ((size_t)ng * K_DIM + k) * O_DIM + og] = o4;
}

extern "C" void kernel_launch(void* const* d_in, const int* in_sizes, int n_in,
                              void* d_out, int out_size, void* d_ws, size_t ws_size,
                              hipStream_t stream) {
    (void)out_size;
    static const int EXP[11] = {25165824, 32768, 24576, 32, 1572864, 64,
                                2097152, 65536, 32, 16, 1};
    int mapi[11];
    bool used[64] = {false};
    for (int s = 0; s < 11; s++) {
        mapi[s] = (s < n_in) ? s : 0;
        for (int j = 0; j < n_in && j < 64; j++) {
            if (!used[j] && in_sizes[j] == EXP[s]) { mapi[s] = j; used[j] = true; break; }
        }
    }
    const float* x        = (const float*)d_in[mapi[0]];
    const float* mask     = (const float*)d_in[mapi[1]];
    const float* Wscore   = (const float*)d_in[mapi[2]];
    const float* Bscore   = (const float*)d_in[mapi[3]];
    const float* Wcap     = (const float*)d_in[mapi[4]];
    const float* Bcap     = (const float*)d_in[mapi[5]];
    const float* Wvote    = (const float*)d_in[mapi[6]];
    const float* Bvote    = (const float*)d_in[mapi[7]];
    const float* beta_use = (const float*)d_in[mapi[8]];
    const float* beta_ign = (const float*)d_in[mapi[9]];
    const int*   iters    = (const int*)d_in[mapi[10]];
    float* out = (float*)d_out;

    const size_t WCAP = (size_t)L_DIM * I_DIM * D_DIM;         // u16 elems
    const size_t WVOT = (size_t)L_DIM * K_DIM * O_DIM * I_DIM; // u16 elems
    const size_t WBYTES = 2 * WCAP * 2 + 2 * WVOT * 2;

    int C = 64;
    {
        const int cands[5] = {1024, 512, 256, 128, 64};
        for (int i = 0; i < 5; i++) {
            size_t need = WBYTES + (size_t)cands[i] * (128 + 8192 + 131072);
            if (need <= ws_size) { C = cands[i]; break; }
        }
    }

    char* ws = (char*)d_ws;
    u16* WcH = (u16*)ws;
    u16* WcL = (u16*)(ws + WCAP * 2);
    u16* WvH = (u16*)(ws + WCAP * 4);
    u16* WvL = (u16*)(ws + WCAP * 4 + WVOT * 2);
    char* dyn = ws + WBYTES;
    float* fa = (float*)dyn;
    float* mu = (float*)(dyn + (size_t)128 * C);
    float* V  = (float*)(dyn + (size_t)128 * C + (size_t)8192 * C);

    prep_wcap<<<dim3(12, 32), 256, 0, stream>>>(Wcap, WcH, WcL);
    prep_wvote<<<dim3(16, 32), 256, 0, stream>>>(Wvote, WvH, WvL);

    for (int nbase = 0; nbase < N_DIM; nbase += C) {
        kernelA<<<dim3(C / 64, 32), 256, 0, stream>>>(
            x, mask, Wscore, Bscore, WcH, WcL, Bcap, mu, fa, nbase, C);
        kernelB<<<dim3(C / 64, 16, 32), 256, 0, stream>>>(
            mu, WvH, WvL, Bvote, V, C);
        kernelC<<<dim3(C), 256, 0, stream>>>(
            V, fa, beta_use, beta_ign, iters, out, nbase, C);
    }
}

// Round 10
// 296.508 us; speedup vs baseline: 1.0333x; 1.0333x over previous
//
#include <hip/hip_runtime.h>
#include <hip/hip_bf16.h>

#define L_DIM 32
#define N_DIM 1024
#define D_DIM 768
#define K_DIM 16
#define I_DIM 64
#define O_DIM 64
#define EPSF 1e-8f
#define PX 72   // padded LDS row (bf16 elems): 144 B

typedef unsigned short u16;
typedef __attribute__((ext_vector_type(8))) short short8;   // 8 bf16 (4 VGPRs)
typedef __attribute__((ext_vector_type(4))) float f32x4;
#define MFMA __builtin_amdgcn_mfma_f32_16x16x32_bf16

__device__ __forceinline__ float bf2f(u16 v) {
    union { unsigned int u; float f; } x; x.u = ((unsigned int)v) << 16; return x.f;
}
__device__ __forceinline__ u16 f2bf(float f) {
    union { float f; unsigned int u; } x; x.f = f;
    unsigned int u = x.u;
    u += 0x7FFFu + ((u >> 16) & 1u);   // RNE
    return (u16)(u >> 16);
}
__device__ __forceinline__ void split2(float v, u16& h, u16& l) {
    u16 hh = f2bf(v);
    h = hh;
    l = f2bf(v - bf2f(hh));
}
// cheap truncation split of float4 -> packed hi uint2 + lo uint2 (exact residual)
__device__ __forceinline__ void store_split4(u16* ph, u16* pl, float4 v) {
    unsigned u0 = __float_as_uint(v.x), u1 = __float_as_uint(v.y);
    unsigned u2 = __float_as_uint(v.z), u3 = __float_as_uint(v.w);
    uint2 H, L;
    H.x = (u0 >> 16) | (u1 & 0xFFFF0000u);
    H.y = (u2 >> 16) | (u3 & 0xFFFF0000u);
    float l0 = v.x - __uint_as_float(u0 & 0xFFFF0000u);
    float l1 = v.y - __uint_as_float(u1 & 0xFFFF0000u);
    float l2 = v.z - __uint_as_float(u2 & 0xFFFF0000u);
    float l3 = v.w - __uint_as_float(u3 & 0xFFFF0000u);
    L.x = (__float_as_uint(l0) >> 16) | (__float_as_uint(l1) & 0xFFFF0000u);
    L.y = (__float_as_uint(l2) >> 16) | (__float_as_uint(l3) & 0xFFFF0000u);
    *(uint2*)ph = H;
    *(uint2*)pl = L;
}

// ---------------------------------------------------------------------------
// Prep 1: Wcap [l][d][i] f32  ->  ws [l][i][d] bf16 hi/lo.  grid (12, 32).
// ---------------------------------------------------------------------------
__global__ __launch_bounds__(256) void prep_wcap(
    const float* __restrict__ W, u16* __restrict__ H, u16* __restrict__ Lo)
{
    const int l = blockIdx.y, d0 = blockIdx.x * 64, t = threadIdx.x;
    __shared__ float tile[64][65];
    #pragma unroll
    for (int p = 0; p < 4; p++) {
        int dd = p * 16 + (t >> 4), i4 = (t & 15) * 4;
        float4 v = *(const float4*)&W[((size_t)l * D_DIM + d0 + dd) * I_DIM + i4];
        tile[dd][i4] = v.x; tile[dd][i4+1] = v.y; tile[dd][i4+2] = v.z; tile[dd][i4+3] = v.w;
    }
    __syncthreads();
    #pragma unroll
    for (int p = 0; p < 4; p++) {
        int i = p * 16 + (t >> 4), dd0 = (t & 15) * 4;
        u16 h[4], lo[4];
        #pragma unroll
        for (int j = 0; j < 4; j++) split2(tile[dd0 + j][i], h[j], lo[j]);
        size_t base = ((size_t)l * I_DIM + i) * D_DIM + d0 + dd0;
        uint2 ph; ph.x = h[0] | ((unsigned)h[1] << 16); ph.y = h[2] | ((unsigned)h[3] << 16);
        uint2 pl; pl.x = lo[0] | ((unsigned)lo[1] << 16); pl.y = lo[2] | ((unsigned)lo[3] << 16);
        *(uint2*)&H[base] = ph;
        *(uint2*)&Lo[base] = pl;
    }
}

// ---------------------------------------------------------------------------
// Prep 2: Wvote [l][k][i][o] f32 -> ws [l][k][o][i] bf16 hi/lo. grid (16, 32).
// ---------------------------------------------------------------------------
__global__ __launch_bounds__(256) void prep_wvote(
    const float* __restrict__ W, u16* __restrict__ H, u16* __restrict__ Lo)
{
    const int l = blockIdx.y, k = blockIdx.x, t = threadIdx.x;
    __shared__ float tile[64][65];
    #pragma unroll
    for (int p = 0; p < 4; p++) {
        int i = p * 16 + (t >> 4), o4 = (t & 15) * 4;
        float4 v = *(const float4*)&W[(((size_t)l * K_DIM + k) * I_DIM + i) * O_DIM + o4];
        tile[i][o4] = v.x; tile[i][o4+1] = v.y; tile[i][o4+2] = v.z; tile[i][o4+3] = v.w;
    }
    __syncthreads();
    #pragma unroll
    for (int p = 0; p < 4; p++) {
        int o = p * 16 + (t >> 4), i0 = (t & 15) * 4;
        u16 h[4], lo[4];
        #pragma unroll
        for (int j = 0; j < 4; j++) split2(tile[i0 + j][o], h[j], lo[j]);
        size_t base = (((size_t)l * K_DIM + k) * O_DIM + o) * I_DIM + i0;
        uint2 ph; ph.x = h[0] | ((unsigned)h[1] << 16); ph.y = h[2] | ((unsigned)h[3] << 16);
        uint2 pl; pl.x = lo[0] | ((unsigned)lo[1] << 16); pl.y = lo[2] | ((unsigned)lo[3] << 16);
        *(uint2*)&H[base] = ph;
        *(uint2*)&Lo[base] = pl;
    }
}

// ---------------------------------------------------------------------------
// Kernel A (MFMA, 32-n tile, reg-prefetch dbuf, 1 barrier/chunk):
//   mu[l,nl,i] = gelu(x·Wcap + Bcap); fa = sigmoid(x·Wscore+Bs)·mask
// grid (nchunk/32, 32), block 256. Wave w owns i-tile w; 2 n-tiles.
// fa computed from f32 regs during staging (no LDS reads -> no conflicts).
// ---------------------------------------------------------------------------
__global__ __launch_bounds__(256) void kernelA(
    const float* __restrict__ x, const float* __restrict__ mask,
    const float* __restrict__ Wscore, const float* __restrict__ Bscore,
    const u16* __restrict__ WcH, const u16* __restrict__ WcL,
    const float* __restrict__ Bcap,
    float* __restrict__ mu_out, float* __restrict__ fa_out,
    int nbase, int nchunk)
{
    const int l   = blockIdx.y;
    const int n0l = blockIdx.x * 32;
    const int t    = threadIdx.x;
    const int w    = t >> 6;
    const int lane = t & 63;
    const int quad = lane >> 4;
    const int ln16 = lane & 15;

    __shared__ u16 xh[2][32][PX], xl[2][32][PX];
    __shared__ float wsc_s[D_DIM];
    __shared__ float bcap_s[64];

    for (int i = t; i < D_DIM; i += 256) wsc_s[i] = Wscore[l * D_DIM + i];
    if (t < 64) bcap_s[t] = Bcap[l * I_DIM + t];

    const int sg = t >> 4;          // staging row group 0..15
    const int sd = (t & 15) * 4;    // staging col offset

    const size_t xoff0 = ((size_t)(nbase + n0l + sg) * L_DIM + l) * D_DIM;
    const size_t xoff1 = ((size_t)(nbase + n0l + 16 + sg) * L_DIM + l) * D_DIM;

    float4 r0 = *(const float4*)&x[xoff0 + sd];
    float4 r1 = *(const float4*)&x[xoff1 + sd];

    __syncthreads();   // wsc_s ready

    f32x4 acc[2] = {{0.f,0.f,0.f,0.f},{0.f,0.f,0.f,0.f}};
    float fa0 = 0.f, fa1 = 0.f;

    for (int ch = 0; ch < 12; ch++) {
        const int buf = ch & 1;
        const int k0 = ch * 64;

        // fa partials from registers (wsc_s reads: 2-way max, free)
        {
            const float* wp = &wsc_s[k0 + sd];
            fa0 += r0.x * wp[0] + r0.y * wp[1] + r0.z * wp[2] + r0.w * wp[3];
            fa1 += r1.x * wp[0] + r1.y * wp[1] + r1.z * wp[2] + r1.w * wp[3];
        }
        // stage regs -> LDS[buf] (trunc hi/lo split)
        store_split4(&xh[buf][sg][sd],      &xl[buf][sg][sd],      r0);
        store_split4(&xh[buf][16 + sg][sd], &xl[buf][16 + sg][sd], r1);
        __syncthreads();

        // prefetch chunk ch+1 (in flight across the MFMA phase)
        if (ch + 1 < 12) {
            const int k1 = k0 + 64;
            r0 = *(const float4*)&x[xoff0 + k1 + sd];
            r1 = *(const float4*)&x[xoff1 + k1 + sd];
        }

        // MFMA on LDS[buf]; weights streamed from global (L2-resident)
        #pragma unroll
        for (int ks = 0; ks < 2; ks++) {
            const int kk = ks * 32;
            size_t wbase = ((size_t)l * I_DIM + (w * 16 + ln16)) * D_DIM + k0 + kk + quad * 8;
            short8 ah = *(const short8*)&WcH[wbase];
            short8 al = *(const short8*)&WcL[wbase];
            #pragma unroll
            for (int c = 0; c < 2; c++) {
                const int n = c * 16 + ln16;
                short8 bh = *(const short8*)&xh[buf][n][kk + quad * 8];
                short8 bl = *(const short8*)&xl[buf][n][kk + quad * 8];
                acc[c] = MFMA(ah, bh, acc[c], 0, 0, 0);
                acc[c] = MFMA(ah, bl, acc[c], 0, 0, 0);
                acc[c] = MFMA(al, bh, acc[c], 0, 0, 0);
            }
        }
        // NOTE: single barrier per chunk is safe: next write to this buf is
        // 2 iterations away, separated by two barriers from these reads.
    }

    // fa reduce over the 16 lanes sharing a row (xor 1,2,4,8 stays in-group)
    fa0 += __shfl_xor(fa0, 1, 64); fa1 += __shfl_xor(fa1, 1, 64);
    fa0 += __shfl_xor(fa0, 2, 64); fa1 += __shfl_xor(fa1, 2, 64);
    fa0 += __shfl_xor(fa0, 4, 64); fa1 += __shfl_xor(fa1, 4, 64);
    fa0 += __shfl_xor(fa0, 8, 64); fa1 += __shfl_xor(fa1, 8, 64);
    if ((t & 15) == 0) {
        float bs = Bscore[l];
        {
            float a = fa0 + bs;
            float sig = 1.f / (1.f + expf(-a));
            float m = mask[(size_t)(nbase + n0l + sg) * L_DIM + l];
            fa_out[(size_t)l * nchunk + n0l + sg] = sig * m;
        }
        {
            float a = fa1 + bs;
            float sig = 1.f / (1.f + expf(-a));
            float m = mask[(size_t)(nbase + n0l + 16 + sg) * L_DIM + l];
            fa_out[(size_t)l * nchunk + n0l + 16 + sg] = sig * m;
        }
    }

    // mu epilogue: D row i = w*16 + quad*4 + r; col n = c*16 + ln16
    #pragma unroll
    for (int c = 0; c < 2; c++) {
        const int n = c * 16 + ln16;
        const int i0 = w * 16 + quad * 4;
        float4 o;
        float* op = (float*)&o;
        #pragma unroll
        for (int r = 0; r < 4; r++) {
            float v = acc[c][r] + bcap_s[i0 + r];
            op[r] = 0.5f * v * (1.f + erff(v * 0.70710678118f));
        }
        *(float4*)&mu_out[((size_t)l * nchunk + n0l + n) * I_DIM + i0] = o;
    }
}

// ---------------------------------------------------------------------------
// Kernel B (MFMA): V[l][k][nl][o] = mu·Wvote + Bvote (f32). grid (nchunk/64,16,32).
// ---------------------------------------------------------------------------
__global__ __launch_bounds__(256) void kernelB(
    const float* __restrict__ mu_in,
    const u16* __restrict__ WvH, const u16* __restrict__ WvL,
    const float* __restrict__ Bvote,
    float* __restrict__ V, int nchunk)
{
    const int l   = blockIdx.z;
    const int k   = blockIdx.y;
    const int n0l = blockIdx.x * 64;
    const int t    = threadIdx.x;
    const int w    = t >> 6;
    const int lane = t & 63;
    const int quad = lane >> 4;
    const int ln16 = lane & 15;

    __shared__ u16 mh[64][PX], ml[64][PX];
    __shared__ float bvote_s[64];

    if (t < 64) bvote_s[t] = Bvote[((size_t)l * K_DIM + k) * O_DIM + t];

    #pragma unroll
    for (int p = 0; p < 4; p++) {
        int n = p * 16 + (t >> 4), i0 = (t & 15) * 4;
        float4 v = *(const float4*)&mu_in[((size_t)l * nchunk + n0l + n) * I_DIM + i0];
        store_split4(&mh[n][i0], &ml[n][i0], v);
    }
    __syncthreads();

    f32x4 acc[4] = {{0.f,0.f,0.f,0.f},{0.f,0.f,0.f,0.f},{0.f,0.f,0.f,0.f},{0.f,0.f,0.f,0.f}};

    #pragma unroll
    for (int ks = 0; ks < 2; ks++) {
        const int kk = ks * 32;
        size_t wbase = (((size_t)l * K_DIM + k) * O_DIM + (w * 16 + ln16)) * I_DIM + kk + quad * 8;
        short8 ah = *(const short8*)&WvH[wbase];
        short8 al = *(const short8*)&WvL[wbase];
        #pragma unroll
        for (int c = 0; c < 4; c++) {
            const int n = c * 16 + ln16;
            short8 bh = *(const short8*)&mh[n][kk + quad * 8];
            short8 bl = *(const short8*)&ml[n][kk + quad * 8];
            acc[c] = MFMA(ah, bh, acc[c], 0, 0, 0);
            acc[c] = MFMA(ah, bl, acc[c], 0, 0, 0);
            acc[c] = MFMA(al, bh, acc[c], 0, 0, 0);
        }
    }

    #pragma unroll
    for (int c = 0; c < 4; c++) {
        const int n = c * 16 + ln16;
        const int o0 = w * 16 + quad * 4;
        float4 o;
        o.x = acc[c][0] + bvote_s[o0];
        o.y = acc[c][1] + bvote_s[o0 + 1];
        o.z = acc[c][2] + bvote_s[o0 + 2];
        o.w = acc[c][3] + bvote_s[o0 + 3];
        *(float4*)&V[(((size_t)l * K_DIM + k) * nchunk + n0l + n) * O_DIM + o0] = o;
    }
}

// ---------------------------------------------------------------------------
// Kernel C: EM routing, one block per n. V[l][k][n][o].
// ---------------------------------------------------------------------------
__global__ __launch_bounds__(256) void kernelC(
    const float* __restrict__ V, const float* __restrict__ fa_in,
    const float* __restrict__ beta_use, const float* __restrict__ beta_ign,
    const int* __restrict__ iters_p,
    float* __restrict__ out, int nbase, int nchunk)
{
    const int nl = blockIdx.x;
    const int ng = nbase + nl;
    const int t  = threadIdx.x;
    const int k  = t >> 4;
    const int og = (t & 15) << 2;
    int iters = iters_p[0];
    if (iters < 0 || iters > 16) iters = 3;

    __shared__ float fa_s[32];
    __shared__ float bu_s[32];
    __shared__ float R_s[32][17];
    __shared__ float sc_s[32][17];

    if (t < 32) {
        fa_s[t] = fa_in[(size_t)t * nchunk + nl];
        bu_s[t] = beta_use[t];
    }
    for (int idx = t; idx < 512; idx += 256)
        R_s[idx >> 4][idx & 15] = 1.f / 16.f;
    const float bi_k = beta_ign[k];

    float Vr[32][4];
    #pragma unroll
    for (int l = 0; l < 32; l++) {
        float4 v = *(const float4*)&V[(((size_t)l * K_DIM + k) * nchunk + nl) * O_DIM + og];
        Vr[l][0] = v.x; Vr[l][1] = v.y; Vr[l][2] = v.z; Vr[l][3] = v.w;
    }
    __syncthreads();

    float mu_r[4] = {0.f, 0.f, 0.f, 0.f};
    float var_r[4] = {0.f, 0.f, 0.f, 0.f};
    float a_r = 0.f;

    for (int it = 0; it < iters; it++) {
        if (it > 0) {
            float inv2v[4], lvp = 0.f;
            #pragma unroll
            for (int j = 0; j < 4; j++) {
                inv2v[j] = 1.f / (2.f * var_r[j] + EPSF);
                lvp += logf(var_r[j] + EPSF);
            }
            lvp += __shfl_xor(lvp, 1, 64);
            lvp += __shfl_xor(lvp, 2, 64);
            lvp += __shfl_xor(lvp, 4, 64);
            lvp += __shfl_xor(lvp, 8, 64);
            float ls = fminf(a_r, 0.f) - log1pf(expf(-fabsf(a_r)));
            const float cst = ls - 1.f - 1.57079632679f - 0.5f * lvp;
            #pragma unroll
            for (int l = 0; l < 32; l++) {
                float s = 0.f;
                #pragma unroll
                for (int j = 0; j < 4; j++) {
                    float d = Vr[l][j] - mu_r[j];
                    s += d * d * inv2v[j];
                }
                s = -s;
                s += __shfl_xor(s, 1, 64);
                s += __shfl_xor(s, 2, 64);
                s += __shfl_xor(s, 4, 64);
                s += __shfl_xor(s, 8, 64);
                if ((t & 15) == 0) sc_s[l][k] = s + cst;
            }
            __syncthreads();
            {   // parallel softmax over k: row lr = t>>3, 8 threads/row, 2 k each
                const int lr = t >> 3;
                const int c2 = (t & 7) * 2;
                float s0 = sc_s[lr][c2], s1 = sc_s[lr][c2 + 1];
                float m = fmaxf(s0, s1);
                m = fmaxf(m, __shfl_xor(m, 1, 64));
                m = fmaxf(m, __shfl_xor(m, 2, 64));
                m = fmaxf(m, __shfl_xor(m, 4, 64));
                float e0 = expf(s0 - m), e1 = expf(s1 - m);
                float sum = e0 + e1;
                sum += __shfl_xor(sum, 1, 64);
                sum += __shfl_xor(sum, 2, 64);
                sum += __shfl_xor(sum, 4, 64);
                float inv = 1.f / sum;
                R_s[lr][c2]     = e0 * inv;
                R_s[lr][c2 + 1] = e1 * inv;
            }
            __syncthreads();
        }
        float denom = EPSF, a_acc = 0.f;
        float mu_a[4] = {0.f, 0.f, 0.f, 0.f};
        float v2_a[4] = {0.f, 0.f, 0.f, 0.f};
        #pragma unroll
        for (int l = 0; l < 32; l++) {
            float Du = fa_s[l] * R_s[l][k];
            denom += Du;
            a_acc += bu_s[l] * Du - bi_k * (fa_s[l] - Du);
            #pragma unroll
            for (int j = 0; j < 4; j++) {
                float dv = Du * Vr[l][j];
                mu_a[j] += dv;
                v2_a[j] += dv * Vr[l][j];
            }
        }
        float invd = 1.f / denom;
        #pragma unroll
        for (int j = 0; j < 4; j++) {
            mu_r[j] = mu_a[j] * invd;
            var_r[j] = fmaxf(v2_a[j] * invd - mu_r[j] * mu_r[j], 0.f);
        }
        a_r = a_acc;
    }

    if ((t & 15) == 0) out[(size_t)ng * K_DIM + k] = a_r;
    float4 o4;
    o4.x = mu_r[0]; o4.y = mu_r[1]; o4.z = mu_r[2]; o4.w = mu_r[3];
    *(float4*)&out[(size_t)N_DIM * K_DIM + ((size_t)ng * K_DIM + k) * O_DIM + og] = o4;
}

extern "C" void kernel_launch(void* const* d_in, const int* in_sizes, int n_in,
                              void* d_out, int out_size, void* d_ws, size_t ws_size,
                              hipStream_t stream) {
    (void)out_size;
    static const int EXP[11] = {25165824, 32768, 24576, 32, 1572864, 64,
                                2097152, 65536, 32, 16, 1};
    int mapi[11];
    bool used[64] = {false};
    for (int s = 0; s < 11; s++) {
        mapi[s] = (s < n_in) ? s : 0;
        for (int j = 0; j < n_in && j < 64; j++) {
            if (!used[j] && in_sizes[j] == EXP[s]) { mapi[s] = j; used[j] = true; break; }
        }
    }
    const float* x        = (const float*)d_in[mapi[0]];
    const float* mask     = (const float*)d_in[mapi[1]];
    const float* Wscore   = (const float*)d_in[mapi[2]];
    const float* Bscore   = (const float*)d_in[mapi[3]];
    const float* Wcap     = (const float*)d_in[mapi[4]];
    const float* Bcap     = (const float*)d_in[mapi[5]];
    const float* Wvote    = (const float*)d_in[mapi[6]];
    const float* Bvote    = (const float*)d_in[mapi[7]];
    const float* beta_use = (const float*)d_in[mapi[8]];
    const float* beta_ign = (const float*)d_in[mapi[9]];
    const int*   iters    = (const int*)d_in[mapi[10]];
    float* out = (float*)d_out;

    const size_t WCAP = (size_t)L_DIM * I_DIM * D_DIM;         // u16 elems
    const size_t WVOT = (size_t)L_DIM * K_DIM * O_DIM * I_DIM; // u16 elems
    const size_t WBYTES = 2 * WCAP * 2 + 2 * WVOT * 2;

    int C = 64;
    {
        const int cands[5] = {1024, 512, 256, 128, 64};
        for (int i = 0; i < 5; i++) {
            size_t need = WBYTES + (size_t)cands[i] * (128 + 8192 + 131072);
            if (need <= ws_size) { C = cands[i]; break; }
        }
    }

    char* ws = (char*)d_ws;
    u16* WcH = (u16*)ws;
    u16* WcL = (u16*)(ws + WCAP * 2);
    u16* WvH = (u16*)(ws + WCAP * 4);
    u16* WvL = (u16*)(ws + WCAP * 4 + WVOT * 2);
    char* dyn = ws + WBYTES;
    float* fa = (float*)dyn;
    float* mu = (float*)(dyn + (size_t)128 * C);
    float* V  = (float*)(dyn + (size_t)128 * C + (size_t)8192 * C);

    prep_wcap<<<dim3(12, 32), 256, 0, stream>>>(Wcap, WcH, WcL);
    prep_wvote<<<dim3(16, 32), 256, 0, stream>>>(Wvote, WvH, WvL);

    for (int nbase = 0; nbase < N_DIM; nbase += C) {
        kernelA<<<dim3(C / 32, 32), 256, 0, stream>>>(
            x, mask, Wscore, Bscore, WcH, WcL, Bcap, mu, fa, nbase, C);
        kernelB<<<dim3(C / 64, 16, 32), 256, 0, stream>>>(
            mu, WvH, WvL, Bvote, V, C);
        kernelC<<<dim3(C), 256, 0, stream>>>(
            V, fa, beta_use, beta_ign, iters, out, nbase, C);
    }
}